// Round 11
// baseline (235.229 us; speedup 1.0000x reference)
//
#include <hip/hip_runtime.h>
#include <hip/hip_bf16.h>

// Problem: B=4, S=2048, D=1024, H=16, E=64
#define B_ 4
#define S_ 2048
#define D_ 1024
#define H_ 16
#define E_ 64
#define M_ (B_*S_)      // 8192 rows
#define NQKV_ 3072

typedef __attribute__((ext_vector_type(8))) short bf16x8;
typedef __attribute__((ext_vector_type(4))) float f32x4;
typedef __attribute__((ext_vector_type(16))) float f32x16;
typedef __attribute__((ext_vector_type(4))) unsigned short u16x4;
typedef unsigned short u16;

#define QSCALE 0.18033688011f   // log2(e)/8: folded into Q at GEMM epilogue
#define AS1 __attribute__((address_space(1)))
#define AS3 __attribute__((address_space(3)))

// XOR swizzle on 16B slots within a 128B row (session-verified: 0 conflicts)
#define SWZ(r) ((((r) & 7) ^ ((((r) >> 3) & 3) << 1)) << 4)

static __device__ __forceinline__ u16 f2bf(float f) {
  unsigned u = __builtin_bit_cast(unsigned, f);
  unsigned r = (u + 0x7FFFu + ((u >> 16) & 1u)) >> 16;
  return (u16)r;
}

// packed RNE f32x2 -> bf16x2 (low = a, high = b)
static __device__ __forceinline__ unsigned pk2(float a, float b) {
  unsigned r;
  asm("v_cvt_pk_bf16_f32 %0, %1, %2" : "=v"(r) : "v"(a), "v"(b));
  return r;
}

// ---------------- conversion kernels ----------------

__global__ __launch_bounds__(256) void cvt4(const float* __restrict__ in,
                                            u16* __restrict__ out, int n4) {
  int i = blockIdx.x * 256 + threadIdx.x;
  if (i >= n4) return;
  f32x4 v = ((const f32x4*)in)[i];
  u16x4 o;
  o.x = f2bf(v.x); o.y = f2bf(v.y); o.z = f2bf(v.z); o.w = f2bf(v.w);
  ((u16x4*)out)[i] = o;
}

// Wq/Wk/Wv [H,D,E] -> Wt [3072][1024] (Wt[n][k] = W[k][n]) via LDS transpose.
__global__ __launch_bounds__(256) void cvt_wqkv(const float* __restrict__ Wq,
                                                const float* __restrict__ Wk,
                                                const float* __restrict__ Wv,
                                                u16* __restrict__ Wt) {
  __shared__ float t[64][65];
  const int h = blockIdx.x >> 4;
  const int db = (blockIdx.x & 15) * 64;
  const int tid = threadIdx.x;
  const float* srcs[3] = {Wq, Wk, Wv};
#pragma unroll
  for (int m = 0; m < 3; ++m) {
    const float* src = srcs[m] + (size_t)h * 65536 + (size_t)db * 64;
    __syncthreads();
#pragma unroll
    for (int i = 0; i < 16; ++i) {
      int idx = i * 256 + tid;
      int d = idx >> 6, e = idx & 63;
      t[e][d] = src[d * 64 + e];
    }
    __syncthreads();
    u16* dst = Wt + (size_t)(m * 1024 + h * 64) * 1024 + db;
#pragma unroll
    for (int i = 0; i < 16; ++i) {
      int idx = i * 256 + tid;
      int e = idx >> 6, d = idx & 63;
      dst[(size_t)e * 1024 + d] = f2bf(t[e][d]);
    }
  }
}

// -------- QKV GEMM: 256x192 tile, BK=64, SINGLE-buffer, 2 blocks/CU -------
// C[8192,3072] = X[8192,1024] * Wqkv[3072,1024]^T.
// 8 waves (2M x 4N), per-wave 128x48: acc[8][3], 48 MFMA + 22 ds_read_b128
// per K-tile per wave.  Single-buffered LDS (56 KB) -> 2 blocks/CU
// (16 waves/CU): the m97 cross-block overlap mechanism hides the barrier
// drain (R10's 112KB dbuf at 1 block/CU was neutral: MfmaUtil stuck at 22%).
// T2 swizzle via inverse-swizzled global_load_lds source (rule 21), T5
// setprio.  Epilogue regions: c<1024 Q (pre-scaled), c<2048 K, c>=2048 V ->
// transposed sigma-permuted Vt (all session-verified formulas).

__global__ __launch_bounds__(512, 4) void gemm_qkv(const u16* __restrict__ A,
                                                   const u16* __restrict__ Bt,
                                                   u16* __restrict__ QK,
                                                   u16* __restrict__ Vt) {
  __shared__ u16 As[256 * 64];       // 32 KB
  __shared__ u16 Bs[192 * 64];       // 24 KB
  const int tid = threadIdx.x;
  const int lane = tid & 63, wv = tid >> 6;
  const int ll = lane & 15, lg = lane >> 4;
  const int wm = wv >> 2, wn = wv & 3;       // 2 x 4 wave grid
  const int bm = blockIdx.x, bn = blockIdx.y;

  // staging sources (K-tile 0), inverse-swizzled cols; LDS dest is linear
  const int sr = tid >> 3;                   // row-sub 0..63
  const int scb = (tid & 7) * 16;            // 16B slot byte
  const char* asrc[4];
  const char* bsrc[3];
#pragma unroll
  for (int i = 0; i < 4; ++i) {
    int row = i * 64 + sr;
    asrc[i] = (const char*)(A + (size_t)(bm * 256 + row) * 1024) + (scb ^ SWZ(row));
  }
#pragma unroll
  for (int i = 0; i < 3; ++i) {
    int row = i * 64 + sr;
    bsrc[i] = (const char*)(Bt + (size_t)(bn * 192 + row) * 1024) + (scb ^ SWZ(row));
  }

  f32x4 acc[8][3] = {};

  for (int t = 0; t < 16; ++t) {
    const size_t adv = (size_t)t * 128;      // BK=64 elems * 2B
    char* ad = (char*)&As[0] + tid * 16;
    char* bd = (char*)&Bs[0] + tid * 16;
#pragma unroll
    for (int i = 0; i < 4; ++i)
      __builtin_amdgcn_global_load_lds((const AS1 void*)(asrc[i] + adv),
                                       (AS3 void*)(ad + i * 8192), 16, 0, 0);
#pragma unroll
    for (int i = 0; i < 3; ++i)
      __builtin_amdgcn_global_load_lds((const AS1 void*)(bsrc[i] + adv),
                                       (AS3 void*)(bd + i * 8192), 16, 0, 0);
    __syncthreads();

    const char* ab = (const char*)&As[0];
    const char* bb = (const char*)&Bs[0];

    bf16x8 bf_[3][2];
#pragma unroll
    for (int ni = 0; ni < 3; ++ni) {
      int row = wn * 48 + ni * 16 + ll;
#pragma unroll
      for (int ks = 0; ks < 2; ++ks)
        bf_[ni][ks] = *(const bf16x8*)(bb + row * 128 +
                                       ((ks * 64 + lg * 16) ^ SWZ(row)));
    }
    __builtin_amdgcn_s_setprio(1);
#pragma unroll
    for (int mi = 0; mi < 8; ++mi) {
      int row = wm * 128 + mi * 16 + ll;
#pragma unroll
      for (int ks = 0; ks < 2; ++ks) {
        bf16x8 af = *(const bf16x8*)(ab + row * 128 +
                                     ((ks * 64 + lg * 16) ^ SWZ(row)));
#pragma unroll
        for (int ni = 0; ni < 3; ++ni)
          acc[mi][ni] = __builtin_amdgcn_mfma_f32_16x16x32_bf16(
              af, bf_[ni][ks], acc[mi][ni], 0, 0, 0);
      }
    }
    __builtin_amdgcn_s_setprio(0);
    __syncthreads();
  }

  // epilogue (per-fragment region: Q scaled / K plain / V -> sigma Vt)
  const int sig = (((lg & 1) << 1) | (lg >> 1)) << 2;   // sigma on 4-blocks
#pragma unroll
  for (int mi = 0; mi < 8; ++mi) {
#pragma unroll
    for (int ni = 0; ni < 3; ++ni) {
      int c = bn * 192 + wn * 48 + ni * 16 + ll;
      int r0 = bm * 256 + wm * 128 + mi * 16 + lg * 4;   // token of j=0
      if (c >= 2048) {                                   // V region
        int bb2 = r0 >> 11, s0 = r0 & 2047;
        int s0p = (s0 & ~15) | sig;
        u16x4 pkv;
        pkv.x = f2bf(acc[mi][ni][0]); pkv.y = f2bf(acc[mi][ni][1]);
        pkv.z = f2bf(acc[mi][ni][2]); pkv.w = f2bf(acc[mi][ni][3]);
        *(u16x4*)&Vt[((size_t)(bb2 * 1024 + (c - 2048))) * 2048 + s0p] = pkv;
      } else {
        const float qs = (c < 1024) ? QSCALE : 1.0f;
#pragma unroll
        for (int j = 0; j < 4; ++j)
          QK[(size_t)(r0 + j) * 2048 + c] = f2bf(acc[mi][ni][j] * qs);
      }
    }
  }
}

// ---------------- GEMM: C[M,N] = A[M,K] * Bt[N,K]^T (out-proj) ------------
// 128x128 tile, BK=32, 4 waves (2x2 of 64x64), global_load_lds w=16.

template<bool FP32OUT>
__global__ __launch_bounds__(256) void gemm_bt(const u16* __restrict__ A,
                                               const u16* __restrict__ Bt,
                                               void* __restrict__ Cv, int ldC,
                                               u16* __restrict__ Vt,
                                               const float* __restrict__ bias,
                                               int M, int N, int K) {
  __shared__ u16 As[128 * 32];
  __shared__ u16 Bs[128 * 32];
  const int tid = threadIdx.x;
  const int lane = tid & 63, wid = tid >> 6;
  const int bm = blockIdx.x, bn = blockIdx.y;
  const int wr = wid >> 1, wc = wid & 1;
  const int ll = lane & 15, lg = lane >> 4;

  f32x4 acc[4][4] = {};

  const int srow = lane >> 2;
  const int scol = (lane & 3) * 8;

  for (int k0 = 0; k0 < K; k0 += 32) {
#pragma unroll
    for (int p = 0; p < 2; ++p) {
      int row = p * 64 + wid * 16 + srow;
      const u16* ga = A + (size_t)(bm * 128 + row) * K + k0 + scol;
      __builtin_amdgcn_global_load_lds(
          (const AS1 void*)ga, (AS3 void*)(As + p * 2048 + wid * 512), 16, 0, 0);
      const u16* gb = Bt + (size_t)(bn * 128 + row) * K + k0 + scol;
      __builtin_amdgcn_global_load_lds(
          (const AS1 void*)gb, (AS3 void*)(Bs + p * 2048 + wid * 512), 16, 0, 0);
    }
    __syncthreads();
    bf16x8 af[4], bfr[4];
#pragma unroll
    for (int mi = 0; mi < 4; ++mi)
      af[mi] = *(const bf16x8*)&As[(wr * 64 + mi * 16 + ll) * 32 + lg * 8];
#pragma unroll
    for (int ni = 0; ni < 4; ++ni)
      bfr[ni] = *(const bf16x8*)&Bs[(wc * 64 + ni * 16 + ll) * 32 + lg * 8];
#pragma unroll
    for (int mi = 0; mi < 4; ++mi)
#pragma unroll
      for (int ni = 0; ni < 4; ++ni)
        acc[mi][ni] = __builtin_amdgcn_mfma_f32_16x16x32_bf16(af[mi], bfr[ni],
                                                              acc[mi][ni], 0, 0, 0);
    __syncthreads();
  }

  const int crow0 = bm * 128 + wr * 64;
  const int ccol0 = bn * 128 + wc * 64 + ll;
#pragma unroll
  for (int mi = 0; mi < 4; ++mi) {
#pragma unroll
    for (int ni = 0; ni < 4; ++ni) {
      int c = ccol0 + ni * 16;
#pragma unroll
      for (int j = 0; j < 4; ++j) {
        int r = crow0 + mi * 16 + lg * 4 + j;
        if (FP32OUT) {
          ((float*)Cv)[(size_t)r * ldC + c] = acc[mi][ni][j] + bias[c];
        } else {
          ((u16*)Cv)[(size_t)r * ldC + c] = f2bf(acc[mi][ni][j]);
        }
      }
    }
  }
}

// ------- flash attention (causal): 8-wave, QBLK=256, 32x32 MFMA -----------
// (unchanged from R9 — verified)

__global__ __launch_bounds__(512, 2) void attn(const u16* __restrict__ QK,
                                               const u16* __restrict__ Vt,
                                               u16* __restrict__ AO) {
  __shared__ u16 Klds[4][4096];      // ring of [key 0..63][e 0..63], swizzled
  __shared__ u16 Vlds[4][4096];      // ring of V^T [e][key-slot], swizzled

  const int wg = blockIdx.x;                 // 0..255
  const int lin = (wg & 7) * 32 + (wg >> 3);
  const int bh = lin >> 2, pr = lin & 3;
  const int b = bh >> 4, h = bh & 15;
  const int tid = threadIdx.x;
  const int lane = tid & 63, wv = tid >> 6;  // 8 waves
  const int lq = lane & 31, hi = lane >> 5;

  const int srow = tid >> 3;                 // 0..63
  const int scolb = ((tid & 7) * 16) ^ SWZ(srow);
  const char* ksrc = (const char*)(QK + (size_t)(b * S_ + srow) * 2048 + 1024 + h * E_) + scolb;
  const char* vsrc = (const char*)(Vt + (size_t)(bh * 64 + srow) * 2048) + scolb;

  const int nktA = 4 * pr + 4;
  const int NS = 36;

  auto stage = [&](int sq, int kb) {
    char* kd = (char*)&Klds[0][0] + (sq & 3) * 8192 + wv * 1024;
    char* vd = (char*)&Vlds[0][0] + (sq & 3) * 8192 + wv * 1024;
    __builtin_amdgcn_global_load_lds((const AS1 void*)(ksrc + (size_t)kb * 4096),
                                     (AS3 void*)kd, 16, 0, 0);
    __builtin_amdgcn_global_load_lds((const AS1 void*)(vsrc + kb * 2),
                                     (AS3 void*)vd, 16, 0, 0);
  };

  stage(0, 0);
  stage(1, (1 < nktA ? 1 : 1 - nktA) * 64);

  int seq = 0;
  for (int ph = 0; ph < 2; ++ph) {
    const int qt = ph ? 7 - pr : pr;
    const int nkt = 4 * qt + 4;
    const int qw0 = qt * 256 + wv * 32;
    const int q = qw0 + lq;

    const u16* qp = QK + (size_t)(b * S_ + q) * 2048 + h * E_;
    bf16x8 qf[4];
#pragma unroll
    for (int c = 0; c < 4; ++c)
      qf[c] = *(const bf16x8*)(qp + c * 16 + hi * 8);

    float m_run = -INFINITY, l_part = 0.f;
    f32x16 o0 = {}, o1 = {};

    for (int kt = 0; kt < nkt; ++kt, ++seq) {
      if (seq + 2 < NS) {
        int s2 = seq + 2;
        stage(s2, (s2 < nktA ? s2 : s2 - nktA) * 64);
      }
      if (seq < NS - 2)       asm volatile("s_waitcnt vmcnt(4)" ::: "memory");
      else if (seq == NS - 2) asm volatile("s_waitcnt vmcnt(2)" ::: "memory");
      else                    asm volatile("s_waitcnt vmcnt(0)" ::: "memory");
      __builtin_amdgcn_s_barrier();

      const int kb = kt * 64;
      if (kb > qw0 + 31) continue;         // fully masked for this wave
      const char* kbuf = (const char*)&Klds[0][0] + (seq & 3) * 8192;
      const char* vbuf = (const char*)&Vlds[0][0] + (seq & 3) * 8192;

      auto half = [&](int kb2) __attribute__((always_inline)) {
        f32x16 sc = {};
        __builtin_amdgcn_s_setprio(1);
        const int krow = kb2 * 32 + lq;
#pragma unroll
        for (int c = 0; c < 4; ++c) {
          bf16x8 kf = *(const bf16x8*)(kbuf + krow * 128 +
                                       ((c * 32 + hi * 16) ^ SWZ(krow)));
          sc = __builtin_amdgcn_mfma_f32_32x32x16_bf16(kf, qf[c], sc, 0, 0, 0);
        }
        __builtin_amdgcn_s_setprio(0);

        if (kb + kb2 * 32 + 31 > qw0) {
#pragma unroll
          for (int r = 0; r < 16; ++r) {
            int key = kb + kb2 * 32 + (r & 3) + 8 * (r >> 2) + 4 * hi;
            if (key > q) sc[r] = -1e30f;
          }
        }

        float pm = sc[0];
#pragma unroll
        for (int r = 1; r < 16; ++r) pm = fmaxf(pm, sc[r]);
        if (__any(pm - m_run > 8.0f)) {
          float g = fmaxf(pm, __shfl_xor(pm, 32, 64));
          float mn = fmaxf(m_run, g);
          float corr = exp2f(m_run - mn);
          m_run = mn;
          l_part *= corr;
          o0 *= corr;
          o1 *= corr;
        }

        float p[16];
#pragma unroll
        for (int r = 0; r < 16; ++r) {
          p[r] = exp2f(sc[r] - m_run);
          l_part += p[r];
        }
        __builtin_amdgcn_s_setprio(1);
#pragma unroll
        for (int gg = 0; gg < 2; ++gg) {
          union { unsigned w[4]; bf16x8 v; } pf;
          pf.w[0] = pk2(p[gg * 8 + 0], p[gg * 8 + 1]);
          pf.w[1] = pk2(p[gg * 8 + 2], p[gg * 8 + 3]);
          pf.w[2] = pk2(p[gg * 8 + 4], p[gg * 8 + 5]);
          pf.w[3] = pk2(p[gg * 8 + 6], p[gg * 8 + 7]);
          const int g = kb2 * 2 + gg;
          {
            bf16x8 vf = *(const bf16x8*)(vbuf + lq * 128 +
                                         ((g * 32 + hi * 16) ^ SWZ(lq)));
            o0 = __builtin_amdgcn_mfma_f32_32x32x16_bf16(vf, pf.v, o0, 0, 0, 0);
          }
          {
            const int er = 32 + lq;
            bf16x8 vf = *(const bf16x8*)(vbuf + er * 128 +
                                         ((g * 32 + hi * 16) ^ SWZ(er)));
            o1 = __builtin_amdgcn_mfma_f32_32x32x16_bf16(vf, pf.v, o1, 0, 0, 0);
          }
        }
        __builtin_amdgcn_s_setprio(0);
      };

      half(0);
      if (kb + 32 <= qw0 + 31) half(1);
    }

    float l = l_part + __shfl_xor(l_part, 32, 64);
    float rl = 1.0f / l;

#pragma unroll
    for (int qd = 0; qd < 4; ++qd) {
      u16x4 w0, w1;
#pragma unroll
      for (int j = 0; j < 4; ++j) {
        w0[j] = f2bf(o0[qd * 4 + j] * rl);
        w1[j] = f2bf(o1[qd * 4 + j] * rl);
      }
      const size_t base = (size_t)(b * S_ + q) * D_ + h * E_ + 8 * qd + 4 * hi;
      *(u16x4*)&AO[base] = w0;
      *(u16x4*)&AO[base + 32] = w1;
    }
  }
}

// ---------------- launcher ----------------

extern "C" void kernel_launch(void* const* d_in, const int* in_sizes, int n_in,
                              void* d_out, int out_size, void* d_ws, size_t ws_size,
                              hipStream_t stream) {
  const float* embedded = (const float*)d_in[0];
  const float* Wq = (const float*)d_in[1];
  const float* Wk = (const float*)d_in[2];
  const float* Wv = (const float*)d_in[3];
  const float* Wo = (const float*)d_in[4];
  const float* bo = (const float*)d_in[5];
  float* out = (float*)d_out;

  char* ws = (char*)d_ws;
  u16* X    = (u16*)(ws);                     // [8192][1024]  16 MiB @ 0
  u16* Wqkv = (u16*)(ws + (16u << 20));       // [3072][1024]   6 MiB @ 16M
  u16* WoT  = (u16*)(ws + (22u << 20));       // [1024][1024]   2 MiB @ 22M
  u16* QK   = (u16*)(ws + (24u << 20));       // [8192][2048]  32 MiB @ 24M
  u16* Vt   = (u16*)(ws + (56u << 20));       // [64][64][2048] 16 MiB @ 56M
  u16* AO   = (u16*)(ws + (72u << 20));       // [8192][1024]  16 MiB @ 72M

  // 1) embedded fp32 -> bf16
  cvt4<<<8192, 256, 0, stream>>>(embedded, X, 2097152);
  // 2) W_qkv repack+cast (LDS-transpose, coalesced both sides)
  cvt_wqkv<<<256, 256, 0, stream>>>(Wq, Wk, Wv, Wqkv);
  // 3) Wo cast
  cvt4<<<1024, 256, 0, stream>>>(Wo, WoT, 262144);
  // 4) QKV projection: 256x192 single-buffer, 2 blocks/CU (Q pre-scaled,
  //    V -> sigma Vt)
  gemm_qkv<<<dim3(32, 16), 512, 0, stream>>>(X, Wqkv, QK, Vt);
  // 5) causal flash attention (8-wave, 32x32, counted-vmcnt ring)
  attn<<<256, 512, 0, stream>>>(QK, Vt, AO);
  // 6) output projection + bias -> fp32 d_out
  gemm_bt<true><<<dim3(64, 8), 256, 0, stream>>>(AO, WoT, out, 1024, nullptr,
                                                 bo, M_, 1024, 1024);
}

// Round 12
// 184.727 us; speedup vs baseline: 1.2734x; 1.2734x over previous
//
#include <hip/hip_runtime.h>
#include <hip/hip_bf16.h>

// Problem: B=4, S=2048, D=1024, H=16, E=64
#define B_ 4
#define S_ 2048
#define D_ 1024
#define H_ 16
#define E_ 64
#define M_ (B_*S_)      // 8192 rows
#define NQKV_ 3072

typedef __attribute__((ext_vector_type(8))) short bf16x8;
typedef __attribute__((ext_vector_type(4))) float f32x4;
typedef __attribute__((ext_vector_type(16))) float f32x16;
typedef __attribute__((ext_vector_type(4))) unsigned short u16x4;
typedef unsigned short u16;

#define QSCALE 0.18033688011f   // log2(e)/8: folded into Q at GEMM epilogue
#define AS1 __attribute__((address_space(1)))
#define AS3 __attribute__((address_space(3)))

// XOR swizzle on 16B slots within a 128B row (session-verified: 0 conflicts)
#define SWZ(r) ((((r) & 7) ^ ((((r) >> 3) & 3) << 1)) << 4)

static __device__ __forceinline__ u16 f2bf(float f) {
  unsigned u = __builtin_bit_cast(unsigned, f);
  unsigned r = (u + 0x7FFFu + ((u >> 16) & 1u)) >> 16;
  return (u16)r;
}

// packed RNE f32x2 -> bf16x2 (low = a, high = b)
static __device__ __forceinline__ unsigned pk2(float a, float b) {
  unsigned r;
  asm("v_cvt_pk_bf16_f32 %0, %1, %2" : "=v"(r) : "v"(a), "v"(b));
  return r;
}

// ---------------- conversion kernels ----------------

__global__ __launch_bounds__(256) void cvt4(const float* __restrict__ in,
                                            u16* __restrict__ out, int n4) {
  int i = blockIdx.x * 256 + threadIdx.x;
  if (i >= n4) return;
  f32x4 v = ((const f32x4*)in)[i];
  u16x4 o;
  o.x = f2bf(v.x); o.y = f2bf(v.y); o.z = f2bf(v.z); o.w = f2bf(v.w);
  ((u16x4*)out)[i] = o;
}

// Wq/Wk/Wv [H,D,E] -> Wt [3072][1024] (Wt[n][k] = W[k][n]) via LDS transpose.
__global__ __launch_bounds__(256) void cvt_wqkv(const float* __restrict__ Wq,
                                                const float* __restrict__ Wk,
                                                const float* __restrict__ Wv,
                                                u16* __restrict__ Wt) {
  __shared__ float t[64][65];
  const int h = blockIdx.x >> 4;
  const int db = (blockIdx.x & 15) * 64;
  const int tid = threadIdx.x;
  const float* srcs[3] = {Wq, Wk, Wv};
#pragma unroll
  for (int m = 0; m < 3; ++m) {
    const float* src = srcs[m] + (size_t)h * 65536 + (size_t)db * 64;
    __syncthreads();
#pragma unroll
    for (int i = 0; i < 16; ++i) {
      int idx = i * 256 + tid;
      int d = idx >> 6, e = idx & 63;
      t[e][d] = src[d * 64 + e];
    }
    __syncthreads();
    u16* dst = Wt + (size_t)(m * 1024 + h * 64) * 1024 + db;
#pragma unroll
    for (int i = 0; i < 16; ++i) {
      int idx = i * 256 + tid;
      int e = idx >> 6, d = idx & 63;
      dst[(size_t)e * 1024 + d] = f2bf(t[e][d]);
    }
  }
}

// -------- QKV GEMM: 256x192, BK=64, dbuf + counted vmcnt + 4-PHASE --------
// C[8192,3072] = X[8192,1024] * Wqkv[3072,1024]^T.
// 8 waves (2M x 4N), per-wave 128x48.  R10 base (verified): dbuf LDS 112KB,
// stage whole next tile at top, boundary vmcnt(7)+barrier.  NEW: each tile's
// compute split into 4 phases over (ks, m-half):
//   {ds_read 7|4 b128 -> s_barrier -> lgkmcnt(0)+sched_barrier -> setprio(1)
//    -> 12 MFMA -> setprio(0) -> s_barrier}
// B-frags (3) reused across the two m-half phases of each ks.  This is the
// m201 per-phase interleave rhythm (the lever that takes 22% -> 45-62%
// MfmaUtil at identical occupancy) grafted onto the proven R10 dataflow.

__global__ __launch_bounds__(512, 1) void gemm_qkv(const u16* __restrict__ A,
                                                   const u16* __restrict__ Bt,
                                                   u16* __restrict__ QK,
                                                   u16* __restrict__ Vt) {
  __shared__ u16 As[2][256 * 64];    // 32 KB per buffer
  __shared__ u16 Bs[2][192 * 64];    // 24 KB per buffer
  const int tid = threadIdx.x;
  const int lane = tid & 63, wv = tid >> 6;
  const int ll = lane & 15, lg = lane >> 4;
  const int wm = wv >> 2, wn = wv & 3;       // 2 x 4 wave grid
  const int bm = blockIdx.x, bn = blockIdx.y;

  // staging sources (K-tile 0), inverse-swizzled cols; LDS dest is linear
  const int sr = tid >> 3;                   // row-sub 0..63
  const int scb = (tid & 7) * 16;            // 16B slot byte
  const char* asrc[4];
  const char* bsrc[3];
#pragma unroll
  for (int i = 0; i < 4; ++i) {
    int row = i * 64 + sr;
    asrc[i] = (const char*)(A + (size_t)(bm * 256 + row) * 1024) + (scb ^ SWZ(row));
  }
#pragma unroll
  for (int i = 0; i < 3; ++i) {
    int row = i * 64 + sr;
    bsrc[i] = (const char*)(Bt + (size_t)(bn * 192 + row) * 1024) + (scb ^ SWZ(row));
  }

  auto stage = [&](int t) {
    const size_t adv = (size_t)t * 128;      // BK=64 elems * 2B
    char* ad = (char*)&As[t & 1][0] + tid * 16;
    char* bd = (char*)&Bs[t & 1][0] + tid * 16;
#pragma unroll
    for (int i = 0; i < 4; ++i)
      __builtin_amdgcn_global_load_lds((const AS1 void*)(asrc[i] + adv),
                                       (AS3 void*)(ad + i * 8192), 16, 0, 0);
#pragma unroll
    for (int i = 0; i < 3; ++i)
      __builtin_amdgcn_global_load_lds((const AS1 void*)(bsrc[i] + adv),
                                       (AS3 void*)(bd + i * 8192), 16, 0, 0);
  };

  f32x4 acc[8][3] = {};

  // per-lane LDS read rows (invariant)
  const int arow0 = wm * 128 + ll;           // + mi*16
  const int brow0 = wn * 48 + ll;            // + ni*16

  stage(0);
  for (int t = 0; t < 16; ++t) {
    if (t + 1 < 16) stage(t + 1);
    if (t < 15) asm volatile("s_waitcnt vmcnt(7)" ::: "memory");
    else        asm volatile("s_waitcnt vmcnt(0)" ::: "memory");
    __builtin_amdgcn_s_barrier();

    const char* ab = (const char*)&As[t & 1][0];
    const char* bb = (const char*)&Bs[t & 1][0];

#pragma unroll
    for (int ks = 0; ks < 2; ++ks) {
      // ---- phase A (m-half 0): read B[ks] + A[mh0][ks], 12 MFMA ----
      bf16x8 bf_[3], af[4];
#pragma unroll
      for (int ni = 0; ni < 3; ++ni) {
        int row = brow0 + ni * 16;
        bf_[ni] = *(const bf16x8*)(bb + row * 128 + ((ks * 64 + lg * 16) ^ SWZ(row)));
      }
#pragma unroll
      for (int mi = 0; mi < 4; ++mi) {
        int row = arow0 + mi * 16;
        af[mi] = *(const bf16x8*)(ab + row * 128 + ((ks * 64 + lg * 16) ^ SWZ(row)));
      }
      __builtin_amdgcn_s_barrier();
      asm volatile("s_waitcnt lgkmcnt(0)" ::: "memory");
      __builtin_amdgcn_sched_barrier(0);
      __builtin_amdgcn_s_setprio(1);
#pragma unroll
      for (int mi = 0; mi < 4; ++mi)
#pragma unroll
        for (int ni = 0; ni < 3; ++ni)
          acc[mi][ni] = __builtin_amdgcn_mfma_f32_16x16x32_bf16(
              af[mi], bf_[ni], acc[mi][ni], 0, 0, 0);
      __builtin_amdgcn_s_setprio(0);
      __builtin_amdgcn_s_barrier();

      // ---- phase B (m-half 1): read A[mh1][ks], reuse B, 12 MFMA ----
      bf16x8 ag[4];
#pragma unroll
      for (int mi = 0; mi < 4; ++mi) {
        int row = arow0 + 64 + mi * 16;
        ag[mi] = *(const bf16x8*)(ab + row * 128 + ((ks * 64 + lg * 16) ^ SWZ(row)));
      }
      __builtin_amdgcn_s_barrier();
      asm volatile("s_waitcnt lgkmcnt(0)" ::: "memory");
      __builtin_amdgcn_sched_barrier(0);
      __builtin_amdgcn_s_setprio(1);
#pragma unroll
      for (int mi = 0; mi < 4; ++mi)
#pragma unroll
        for (int ni = 0; ni < 3; ++ni)
          acc[mi + 4][ni] = __builtin_amdgcn_mfma_f32_16x16x32_bf16(
              ag[mi], bf_[ni], acc[mi + 4][ni], 0, 0, 0);
      __builtin_amdgcn_s_setprio(0);
      __builtin_amdgcn_s_barrier();
    }
  }

  // epilogue (per-fragment region: Q scaled / K plain / V -> sigma Vt)
  const int sig = (((lg & 1) << 1) | (lg >> 1)) << 2;   // sigma on 4-blocks
#pragma unroll
  for (int mi = 0; mi < 8; ++mi) {
#pragma unroll
    for (int ni = 0; ni < 3; ++ni) {
      int c = bn * 192 + wn * 48 + ni * 16 + ll;
      int r0 = bm * 256 + wm * 128 + mi * 16 + lg * 4;   // token of j=0
      if (c >= 2048) {                                   // V region
        int bb2 = r0 >> 11, s0 = r0 & 2047;
        int s0p = (s0 & ~15) | sig;
        u16x4 pkv;
        pkv.x = f2bf(acc[mi][ni][0]); pkv.y = f2bf(acc[mi][ni][1]);
        pkv.z = f2bf(acc[mi][ni][2]); pkv.w = f2bf(acc[mi][ni][3]);
        *(u16x4*)&Vt[((size_t)(bb2 * 1024 + (c - 2048))) * 2048 + s0p] = pkv;
      } else {
        const float qs = (c < 1024) ? QSCALE : 1.0f;
#pragma unroll
        for (int j = 0; j < 4; ++j)
          QK[(size_t)(r0 + j) * 2048 + c] = f2bf(acc[mi][ni][j] * qs);
      }
    }
  }
}

// ---------------- GEMM: C[M,N] = A[M,K] * Bt[N,K]^T (out-proj) ------------
// 128x128 tile, BK=32, 4 waves (2x2 of 64x64), global_load_lds w=16.

template<bool FP32OUT>
__global__ __launch_bounds__(256) void gemm_bt(const u16* __restrict__ A,
                                               const u16* __restrict__ Bt,
                                               void* __restrict__ Cv, int ldC,
                                               u16* __restrict__ Vt,
                                               const float* __restrict__ bias,
                                               int M, int N, int K) {
  __shared__ u16 As[128 * 32];
  __shared__ u16 Bs[128 * 32];
  const int tid = threadIdx.x;
  const int lane = tid & 63, wid = tid >> 6;
  const int bm = blockIdx.x, bn = blockIdx.y;
  const int wr = wid >> 1, wc = wid & 1;
  const int ll = lane & 15, lg = lane >> 4;

  f32x4 acc[4][4] = {};

  const int srow = lane >> 2;
  const int scol = (lane & 3) * 8;

  for (int k0 = 0; k0 < K; k0 += 32) {
#pragma unroll
    for (int p = 0; p < 2; ++p) {
      int row = p * 64 + wid * 16 + srow;
      const u16* ga = A + (size_t)(bm * 128 + row) * K + k0 + scol;
      __builtin_amdgcn_global_load_lds(
          (const AS1 void*)ga, (AS3 void*)(As + p * 2048 + wid * 512), 16, 0, 0);
      const u16* gb = Bt + (size_t)(bn * 128 + row) * K + k0 + scol;
      __builtin_amdgcn_global_load_lds(
          (const AS1 void*)gb, (AS3 void*)(Bs + p * 2048 + wid * 512), 16, 0, 0);
    }
    __syncthreads();
    bf16x8 af[4], bfr[4];
#pragma unroll
    for (int mi = 0; mi < 4; ++mi)
      af[mi] = *(const bf16x8*)&As[(wr * 64 + mi * 16 + ll) * 32 + lg * 8];
#pragma unroll
    for (int ni = 0; ni < 4; ++ni)
      bfr[ni] = *(const bf16x8*)&Bs[(wc * 64 + ni * 16 + ll) * 32 + lg * 8];
#pragma unroll
    for (int mi = 0; mi < 4; ++mi)
#pragma unroll
      for (int ni = 0; ni < 4; ++ni)
        acc[mi][ni] = __builtin_amdgcn_mfma_f32_16x16x32_bf16(af[mi], bfr[ni],
                                                              acc[mi][ni], 0, 0, 0);
    __syncthreads();
  }

  const int crow0 = bm * 128 + wr * 64;
  const int ccol0 = bn * 128 + wc * 64 + ll;
#pragma unroll
  for (int mi = 0; mi < 4; ++mi) {
#pragma unroll
    for (int ni = 0; ni < 4; ++ni) {
      int c = ccol0 + ni * 16;
#pragma unroll
      for (int j = 0; j < 4; ++j) {
        int r = crow0 + mi * 16 + lg * 4 + j;
        if (FP32OUT) {
          ((float*)Cv)[(size_t)r * ldC + c] = acc[mi][ni][j] + bias[c];
        } else {
          ((u16*)Cv)[(size_t)r * ldC + c] = f2bf(acc[mi][ni][j]);
        }
      }
    }
  }
}

// ------- flash attention (causal): 8-wave, QBLK=256, 32x32 MFMA -----------
// (unchanged from R9 — verified)

__global__ __launch_bounds__(512, 2) void attn(const u16* __restrict__ QK,
                                               const u16* __restrict__ Vt,
                                               u16* __restrict__ AO) {
  __shared__ u16 Klds[4][4096];      // ring of [key 0..63][e 0..63], swizzled
  __shared__ u16 Vlds[4][4096];      // ring of V^T [e][key-slot], swizzled

  const int wg = blockIdx.x;                 // 0..255
  const int lin = (wg & 7) * 32 + (wg >> 3);
  const int bh = lin >> 2, pr = lin & 3;
  const int b = bh >> 4, h = bh & 15;
  const int tid = threadIdx.x;
  const int lane = tid & 63, wv = tid >> 6;  // 8 waves
  const int lq = lane & 31, hi = lane >> 5;

  const int srow = tid >> 3;                 // 0..63
  const int scolb = ((tid & 7) * 16) ^ SWZ(srow);
  const char* ksrc = (const char*)(QK + (size_t)(b * S_ + srow) * 2048 + 1024 + h * E_) + scolb;
  const char* vsrc = (const char*)(Vt + (size_t)(bh * 64 + srow) * 2048) + scolb;

  const int nktA = 4 * pr + 4;
  const int NS = 36;

  auto stage = [&](int sq, int kb) {
    char* kd = (char*)&Klds[0][0] + (sq & 3) * 8192 + wv * 1024;
    char* vd = (char*)&Vlds[0][0] + (sq & 3) * 8192 + wv * 1024;
    __builtin_amdgcn_global_load_lds((const AS1 void*)(ksrc + (size_t)kb * 4096),
                                     (AS3 void*)kd, 16, 0, 0);
    __builtin_amdgcn_global_load_lds((const AS1 void*)(vsrc + kb * 2),
                                     (AS3 void*)vd, 16, 0, 0);
  };

  stage(0, 0);
  stage(1, (1 < nktA ? 1 : 1 - nktA) * 64);

  int seq = 0;
  for (int ph = 0; ph < 2; ++ph) {
    const int qt = ph ? 7 - pr : pr;
    const int nkt = 4 * qt + 4;
    const int qw0 = qt * 256 + wv * 32;
    const int q = qw0 + lq;

    const u16* qp = QK + (size_t)(b * S_ + q) * 2048 + h * E_;
    bf16x8 qf[4];
#pragma unroll
    for (int c = 0; c < 4; ++c)
      qf[c] = *(const bf16x8*)(qp + c * 16 + hi * 8);

    float m_run = -INFINITY, l_part = 0.f;
    f32x16 o0 = {}, o1 = {};

    for (int kt = 0; kt < nkt; ++kt, ++seq) {
      if (seq + 2 < NS) {
        int s2 = seq + 2;
        stage(s2, (s2 < nktA ? s2 : s2 - nktA) * 64);
      }
      if (seq < NS - 2)       asm volatile("s_waitcnt vmcnt(4)" ::: "memory");
      else if (seq == NS - 2) asm volatile("s_waitcnt vmcnt(2)" ::: "memory");
      else                    asm volatile("s_waitcnt vmcnt(0)" ::: "memory");
      __builtin_amdgcn_s_barrier();

      const int kb = kt * 64;
      if (kb > qw0 + 31) continue;         // fully masked for this wave
      const char* kbuf = (const char*)&Klds[0][0] + (seq & 3) * 8192;
      const char* vbuf = (const char*)&Vlds[0][0] + (seq & 3) * 8192;

      auto half = [&](int kb2) __attribute__((always_inline)) {
        f32x16 sc = {};
        __builtin_amdgcn_s_setprio(1);
        const int krow = kb2 * 32 + lq;
#pragma unroll
        for (int c = 0; c < 4; ++c) {
          bf16x8 kf = *(const bf16x8*)(kbuf + krow * 128 +
                                       ((c * 32 + hi * 16) ^ SWZ(krow)));
          sc = __builtin_amdgcn_mfma_f32_32x32x16_bf16(kf, qf[c], sc, 0, 0, 0);
        }
        __builtin_amdgcn_s_setprio(0);

        if (kb + kb2 * 32 + 31 > qw0) {
#pragma unroll
          for (int r = 0; r < 16; ++r) {
            int key = kb + kb2 * 32 + (r & 3) + 8 * (r >> 2) + 4 * hi;
            if (key > q) sc[r] = -1e30f;
          }
        }

        float pm = sc[0];
#pragma unroll
        for (int r = 1; r < 16; ++r) pm = fmaxf(pm, sc[r]);
        if (__any(pm - m_run > 8.0f)) {
          float g = fmaxf(pm, __shfl_xor(pm, 32, 64));
          float mn = fmaxf(m_run, g);
          float corr = exp2f(m_run - mn);
          m_run = mn;
          l_part *= corr;
          o0 *= corr;
          o1 *= corr;
        }

        float p[16];
#pragma unroll
        for (int r = 0; r < 16; ++r) {
          p[r] = exp2f(sc[r] - m_run);
          l_part += p[r];
        }
        __builtin_amdgcn_s_setprio(1);
#pragma unroll
        for (int gg = 0; gg < 2; ++gg) {
          union { unsigned w[4]; bf16x8 v; } pf;
          pf.w[0] = pk2(p[gg * 8 + 0], p[gg * 8 + 1]);
          pf.w[1] = pk2(p[gg * 8 + 2], p[gg * 8 + 3]);
          pf.w[2] = pk2(p[gg * 8 + 4], p[gg * 8 + 5]);
          pf.w[3] = pk2(p[gg * 8 + 6], p[gg * 8 + 7]);
          const int g = kb2 * 2 + gg;
          {
            bf16x8 vf = *(const bf16x8*)(vbuf + lq * 128 +
                                         ((g * 32 + hi * 16) ^ SWZ(lq)));
            o0 = __builtin_amdgcn_mfma_f32_32x32x16_bf16(vf, pf.v, o0, 0, 0, 0);
          }
          {
            const int er = 32 + lq;
            bf16x8 vf = *(const bf16x8*)(vbuf + er * 128 +
                                         ((g * 32 + hi * 16) ^ SWZ(er)));
            o1 = __builtin_amdgcn_mfma_f32_32x32x16_bf16(vf, pf.v, o1, 0, 0, 0);
          }
        }
        __builtin_amdgcn_s_setprio(0);
      };

      half(0);
      if (kb + 32 <= qw0 + 31) half(1);
    }

    float l = l_part + __shfl_xor(l_part, 32, 64);
    float rl = 1.0f / l;

#pragma unroll
    for (int qd = 0; qd < 4; ++qd) {
      u16x4 w0, w1;
#pragma unroll
      for (int j = 0; j < 4; ++j) {
        w0[j] = f2bf(o0[qd * 4 + j] * rl);
        w1[j] = f2bf(o1[qd * 4 + j] * rl);
      }
      const size_t base = (size_t)(b * S_ + q) * D_ + h * E_ + 8 * qd + 4 * hi;
      *(u16x4*)&AO[base] = w0;
      *(u16x4*)&AO[base + 32] = w1;
    }
  }
}

// ---------------- launcher ----------------

extern "C" void kernel_launch(void* const* d_in, const int* in_sizes, int n_in,
                              void* d_out, int out_size, void* d_ws, size_t ws_size,
                              hipStream_t stream) {
  const float* embedded = (const float*)d_in[0];
  const float* Wq = (const float*)d_in[1];
  const float* Wk = (const float*)d_in[2];
  const float* Wv = (const float*)d_in[3];
  const float* Wo = (const float*)d_in[4];
  const float* bo = (const float*)d_in[5];
  float* out = (float*)d_out;

  char* ws = (char*)d_ws;
  u16* X    = (u16*)(ws);                     // [8192][1024]  16 MiB @ 0
  u16* Wqkv = (u16*)(ws + (16u << 20));       // [3072][1024]   6 MiB @ 16M
  u16* WoT  = (u16*)(ws + (22u << 20));       // [1024][1024]   2 MiB @ 22M
  u16* QK   = (u16*)(ws + (24u << 20));       // [8192][2048]  32 MiB @ 24M
  u16* Vt   = (u16*)(ws + (56u << 20));       // [64][64][2048] 16 MiB @ 56M
  u16* AO   = (u16*)(ws + (72u << 20));       // [8192][1024]  16 MiB @ 72M

  // 1) embedded fp32 -> bf16
  cvt4<<<8192, 256, 0, stream>>>(embedded, X, 2097152);
  // 2) W_qkv repack+cast (LDS-transpose, coalesced both sides)
  cvt_wqkv<<<256, 256, 0, stream>>>(Wq, Wk, Wv, Wqkv);
  // 3) Wo cast
  cvt4<<<1024, 256, 0, stream>>>(Wo, WoT, 262144);
  // 4) QKV projection: 256x192 dbuf + counted vmcnt + 4-phase interleave
  gemm_qkv<<<dim3(32, 16), 512, 0, stream>>>(X, Wqkv, QK, Vt);
  // 5) causal flash attention (8-wave, 32x32, counted-vmcnt ring)
  attn<<<256, 512, 0, stream>>>(QK, Vt, AO);
  // 6) output projection + bias -> fp32 d_out
  gemm_bt<true><<<dim3(64, 8), 256, 0, stream>>>(AO, WoT, out, 1024, nullptr,
                                                 bo, M_, 1024, 1024);
}

// Round 13
// 180.983 us; speedup vs baseline: 1.2997x; 1.0207x over previous
//
#include <hip/hip_runtime.h>
#include <hip/hip_bf16.h>

// Problem: B=4, S=2048, D=1024, H=16, E=64
#define B_ 4
#define S_ 2048
#define D_ 1024
#define H_ 16
#define E_ 64
#define M_ (B_*S_)      // 8192 rows
#define NQKV_ 3072

typedef __attribute__((ext_vector_type(8))) short bf16x8;
typedef __attribute__((ext_vector_type(4))) float f32x4;
typedef __attribute__((ext_vector_type(16))) float f32x16;
typedef __attribute__((ext_vector_type(4))) unsigned short u16x4;
typedef unsigned short u16;

#define QSCALE 0.18033688011f   // log2(e)/8: folded into Q at GEMM epilogue
#define AS1 __attribute__((address_space(1)))
#define AS3 __attribute__((address_space(3)))

// XOR swizzle for 128-B rows (attn only; BK=32 GEMM rows are 64 B and
// contiguous-1024B per wave read -> conflict-free without swizzle)
#define SWZ(r) ((((r) & 7) ^ ((((r) >> 3) & 3) << 1)) << 4)

static __device__ __forceinline__ u16 f2bf(float f) {
  unsigned u = __builtin_bit_cast(unsigned, f);
  unsigned r = (u + 0x7FFFu + ((u >> 16) & 1u)) >> 16;
  return (u16)r;
}

// packed RNE f32x2 -> bf16x2 (low = a, high = b)
static __device__ __forceinline__ unsigned pk2(float a, float b) {
  unsigned r;
  asm("v_cvt_pk_bf16_f32 %0, %1, %2" : "=v"(r) : "v"(a), "v"(b));
  return r;
}

// ---------------- fused conversion kernel ----------------
// blocks [0, 8192):   embedded fp32 -> bf16 X       (2,097,152 f32x4)
// blocks [8192, 9216): Wo fp32 -> bf16 WoT          (262,144 f32x4)
// blocks [9216, 9472): Wq/Wk/Wv -> Wqkv transposed  (256 LDS-transpose blocks)

__global__ __launch_bounds__(256) void cvt_fused(const float* __restrict__ emb,
                                                 const float* __restrict__ Wo,
                                                 const float* __restrict__ Wq,
                                                 const float* __restrict__ Wk,
                                                 const float* __restrict__ Wv,
                                                 u16* __restrict__ X,
                                                 u16* __restrict__ WoT,
                                                 u16* __restrict__ Wt) {
  __shared__ float t[64][65];
  const int bid = blockIdx.x;
  const int tid = threadIdx.x;
  if (bid < 8192) {
    int i = bid * 256 + tid;
    f32x4 v = ((const f32x4*)emb)[i];
    u16x4 o;
    o.x = f2bf(v.x); o.y = f2bf(v.y); o.z = f2bf(v.z); o.w = f2bf(v.w);
    ((u16x4*)X)[i] = o;
  } else if (bid < 9216) {
    int i = (bid - 8192) * 256 + tid;
    f32x4 v = ((const f32x4*)Wo)[i];
    u16x4 o;
    o.x = f2bf(v.x); o.y = f2bf(v.y); o.z = f2bf(v.z); o.w = f2bf(v.w);
    ((u16x4*)WoT)[i] = o;
  } else {
    const int blk = bid - 9216;
    const int h = blk >> 4;
    const int db = (blk & 15) * 64;
    const float* srcs[3] = {Wq, Wk, Wv};
#pragma unroll
    for (int m = 0; m < 3; ++m) {
      const float* src = srcs[m] + (size_t)h * 65536 + (size_t)db * 64;
      __syncthreads();
#pragma unroll
      for (int i = 0; i < 16; ++i) {
        int idx = i * 256 + tid;
        int d = idx >> 6, e = idx & 63;
        t[e][d] = src[d * 64 + e];
      }
      __syncthreads();
      u16* dst = Wt + (size_t)(m * 1024 + h * 64) * 1024 + db;
#pragma unroll
      for (int i = 0; i < 16; ++i) {
        int idx = i * 256 + tid;
        int e = idx >> 6, d = idx & 63;
        dst[(size_t)e * 1024 + d] = f2bf(t[e][d]);
      }
    }
  }
}

// -------- QKV GEMM: 256x384, BK=32, ring-3, per-wave 128x96 ---------------
// C[8192,3072] = X[8192,1024] * Wqkv[3072,1024]^T.  8 waves (2M x 4N).
// LDS traffic diet: per-wave 128x96 output -> 24.1 B/MFLOP total LDS traffic
// (vs 36.9 for the 128x48 R10 wave tile) — the diagnosed bottleneck.
// BK=32: 64-B LDS rows; a wave's frag read (16 rows x 4 slots) is one
// contiguous 1024-B block -> conflict-free, no swizzle, linear staging.
// Ring-3 buffers + counted vmcnt(10): loads for tiles t+1,t+2 in flight
// across barriers.  Grid 32x8 = 256 blocks = exactly 1 block/CU round.
// Epilogue regions (verified R10): c<1024 Q*QSCALE, c<2048 K, >=2048 V ->
// transposed sigma-permuted Vt.

__global__ __launch_bounds__(512, 2) void gemm_qkv(const u16* __restrict__ A,
                                                   const u16* __restrict__ Bt,
                                                   u16* __restrict__ QK,
                                                   u16* __restrict__ Vt) {
  __shared__ u16 As[3][256 * 32];    // 16 KB per buffer
  __shared__ u16 Bs[3][384 * 32];    // 24 KB per buffer  (total 120 KB)
  const int tid = threadIdx.x;
  const int lane = tid & 63, wv = tid >> 6;
  const int ll = lane & 15, lg = lane >> 4;
  const int wm = wv >> 2, wn = wv & 3;       // 2 x 4 wave grid
  const int bm = blockIdx.x, bn = blockIdx.y;

  // staging sources (K-tile 0); all linear (no swizzle at BK=32)
  const int sr = tid >> 2;                   // 0..127
  const int scb = (tid & 3) * 16;            // byte within 64-B row
  const char* a0 = (const char*)(A + (size_t)(bm * 256 + sr) * 1024) + scb;
  const char* a1 = (const char*)(A + (size_t)(bm * 256 + 128 + sr) * 1024) + scb;
  const char* b0 = (const char*)(Bt + (size_t)(bn * 384 + sr) * 1024) + scb;
  const char* b1 = (const char*)(Bt + (size_t)(bn * 384 + 128 + sr) * 1024) + scb;
  const char* b2 = (const char*)(Bt + (size_t)(bn * 384 + 256 + sr) * 1024) + scb;

  auto stage = [&](int t, int bi) {
    const size_t adv = (size_t)t * 64;       // BK=32 elems * 2 B
    char* ad = (char*)&As[bi][0] + tid * 16;
    char* bd = (char*)&Bs[bi][0] + tid * 16;
    __builtin_amdgcn_global_load_lds((const AS1 void*)(a0 + adv), (AS3 void*)ad, 16, 0, 0);
    __builtin_amdgcn_global_load_lds((const AS1 void*)(a1 + adv), (AS3 void*)(ad + 8192), 16, 0, 0);
    __builtin_amdgcn_global_load_lds((const AS1 void*)(b0 + adv), (AS3 void*)bd, 16, 0, 0);
    __builtin_amdgcn_global_load_lds((const AS1 void*)(b1 + adv), (AS3 void*)(bd + 8192), 16, 0, 0);
    __builtin_amdgcn_global_load_lds((const AS1 void*)(b2 + adv), (AS3 void*)(bd + 16384), 16, 0, 0);
  };

  f32x4 acc[8][6] = {};

  stage(0, 0);
  stage(1, 1);
  for (int t = 0; t < 32; ++t) {
    const int cur = t % 3;
    if (t + 2 < 32) {
      stage(t + 2, (t + 2) % 3);
      asm volatile("s_waitcnt vmcnt(10)" ::: "memory");
    } else if (t + 1 < 32) {
      asm volatile("s_waitcnt vmcnt(5)" ::: "memory");
    } else {
      asm volatile("s_waitcnt vmcnt(0)" ::: "memory");
    }
    __builtin_amdgcn_s_barrier();

    const char* ab = (const char*)&As[cur][0];
    const char* bb = (const char*)&Bs[cur][0];

    bf16x8 bf[6];
#pragma unroll
    for (int ni = 0; ni < 6; ++ni) {
      int row = wn * 96 + ni * 16 + ll;
      bf[ni] = *(const bf16x8*)(bb + row * 64 + lg * 16);
    }
    __builtin_amdgcn_s_setprio(1);
#pragma unroll
    for (int mi = 0; mi < 8; ++mi) {
      int row = wm * 128 + mi * 16 + ll;
      bf16x8 af = *(const bf16x8*)(ab + row * 64 + lg * 16);
#pragma unroll
      for (int ni = 0; ni < 6; ++ni)
        acc[mi][ni] = __builtin_amdgcn_mfma_f32_16x16x32_bf16(
            af, bf[ni], acc[mi][ni], 0, 0, 0);
    }
    __builtin_amdgcn_s_setprio(0);
    __builtin_amdgcn_s_barrier();
  }

  // epilogue (per-fragment region: Q scaled / K plain / V -> sigma Vt)
  const int sig = (((lg & 1) << 1) | (lg >> 1)) << 2;   // sigma on 4-blocks
#pragma unroll
  for (int mi = 0; mi < 8; ++mi) {
#pragma unroll
    for (int ni = 0; ni < 6; ++ni) {
      int c = bn * 384 + wn * 96 + ni * 16 + ll;
      int r0 = bm * 256 + wm * 128 + mi * 16 + lg * 4;   // token of j=0
      if (c >= 2048) {                                   // V region
        int bb2 = r0 >> 11, s0 = r0 & 2047;
        int s0p = (s0 & ~15) | sig;
        u16x4 pkv;
        pkv.x = f2bf(acc[mi][ni][0]); pkv.y = f2bf(acc[mi][ni][1]);
        pkv.z = f2bf(acc[mi][ni][2]); pkv.w = f2bf(acc[mi][ni][3]);
        *(u16x4*)&Vt[((size_t)(bb2 * 1024 + (c - 2048))) * 2048 + s0p] = pkv;
      } else {
        const float qs = (c < 1024) ? QSCALE : 1.0f;
#pragma unroll
        for (int j = 0; j < 4; ++j)
          QK[(size_t)(r0 + j) * 2048 + c] = f2bf(acc[mi][ni][j] * qs);
      }
    }
  }
}

// -------- out-proj GEMM: 256x128, BK=32, ring-3, per-wave 128x32 ----------
// out[8192,1024] = AO[8192,1024] * WoT[1024,1024]^T + bias, fp32 out.
// Same structure as gemm_qkv (traffic 24.9 vs 45.8 B/MFLOP of the 128^2
// version).  Grid 32x8 = 256 blocks = 1 round.

__global__ __launch_bounds__(512, 2) void gemm_out(const u16* __restrict__ A,
                                                   const u16* __restrict__ Bt,
                                                   float* __restrict__ C,
                                                   const float* __restrict__ bias) {
  __shared__ u16 As[3][256 * 32];    // 16 KB per buffer
  __shared__ u16 Bs[3][128 * 32];    // 8 KB per buffer   (total 72 KB)
  const int tid = threadIdx.x;
  const int lane = tid & 63, wv = tid >> 6;
  const int ll = lane & 15, lg = lane >> 4;
  const int wm = wv >> 2, wn = wv & 3;
  const int bm = blockIdx.x, bn = blockIdx.y;

  const int sr = tid >> 2;
  const int scb = (tid & 3) * 16;
  const char* a0 = (const char*)(A + (size_t)(bm * 256 + sr) * 1024) + scb;
  const char* a1 = (const char*)(A + (size_t)(bm * 256 + 128 + sr) * 1024) + scb;
  const char* b0 = (const char*)(Bt + (size_t)(bn * 128 + sr) * 1024) + scb;

  auto stage = [&](int t, int bi) {
    const size_t adv = (size_t)t * 64;
    char* ad = (char*)&As[bi][0] + tid * 16;
    char* bd = (char*)&Bs[bi][0] + tid * 16;
    __builtin_amdgcn_global_load_lds((const AS1 void*)(a0 + adv), (AS3 void*)ad, 16, 0, 0);
    __builtin_amdgcn_global_load_lds((const AS1 void*)(a1 + adv), (AS3 void*)(ad + 8192), 16, 0, 0);
    __builtin_amdgcn_global_load_lds((const AS1 void*)(b0 + adv), (AS3 void*)bd, 16, 0, 0);
  };

  f32x4 acc[8][2] = {};

  stage(0, 0);
  stage(1, 1);
  for (int t = 0; t < 32; ++t) {
    const int cur = t % 3;
    if (t + 2 < 32) {
      stage(t + 2, (t + 2) % 3);
      asm volatile("s_waitcnt vmcnt(6)" ::: "memory");
    } else if (t + 1 < 32) {
      asm volatile("s_waitcnt vmcnt(3)" ::: "memory");
    } else {
      asm volatile("s_waitcnt vmcnt(0)" ::: "memory");
    }
    __builtin_amdgcn_s_barrier();

    const char* ab = (const char*)&As[cur][0];
    const char* bb = (const char*)&Bs[cur][0];

    bf16x8 bf[2];
#pragma unroll
    for (int ni = 0; ni < 2; ++ni) {
      int row = wn * 32 + ni * 16 + ll;
      bf[ni] = *(const bf16x8*)(bb + row * 64 + lg * 16);
    }
    __builtin_amdgcn_s_setprio(1);
#pragma unroll
    for (int mi = 0; mi < 8; ++mi) {
      int row = wm * 128 + mi * 16 + ll;
      bf16x8 af = *(const bf16x8*)(ab + row * 64 + lg * 16);
#pragma unroll
      for (int ni = 0; ni < 2; ++ni)
        acc[mi][ni] = __builtin_amdgcn_mfma_f32_16x16x32_bf16(
            af, bf[ni], acc[mi][ni], 0, 0, 0);
    }
    __builtin_amdgcn_s_setprio(0);
    __builtin_amdgcn_s_barrier();
  }

#pragma unroll
  for (int mi = 0; mi < 8; ++mi) {
#pragma unroll
    for (int ni = 0; ni < 2; ++ni) {
      int c = bn * 128 + wn * 32 + ni * 16 + ll;
      int r0 = bm * 256 + wm * 128 + mi * 16 + lg * 4;
      float bv = bias[c];
#pragma unroll
      for (int j = 0; j < 4; ++j)
        C[(size_t)(r0 + j) * 1024 + c] = acc[mi][ni][j] + bv;
    }
  }
}

// ------- flash attention (causal): 8-wave, QBLK=256, 32x32 MFMA -----------
// (unchanged from R9 — verified)

__global__ __launch_bounds__(512, 2) void attn(const u16* __restrict__ QK,
                                               const u16* __restrict__ Vt,
                                               u16* __restrict__ AO) {
  __shared__ u16 Klds[4][4096];      // ring of [key 0..63][e 0..63], swizzled
  __shared__ u16 Vlds[4][4096];      // ring of V^T [e][key-slot], swizzled

  const int wg = blockIdx.x;                 // 0..255
  const int lin = (wg & 7) * 32 + (wg >> 3);
  const int bh = lin >> 2, pr = lin & 3;
  const int b = bh >> 4, h = bh & 15;
  const int tid = threadIdx.x;
  const int lane = tid & 63, wv = tid >> 6;  // 8 waves
  const int lq = lane & 31, hi = lane >> 5;

  const int srow = tid >> 3;                 // 0..63
  const int scolb = ((tid & 7) * 16) ^ SWZ(srow);
  const char* ksrc = (const char*)(QK + (size_t)(b * S_ + srow) * 2048 + 1024 + h * E_) + scolb;
  const char* vsrc = (const char*)(Vt + (size_t)(bh * 64 + srow) * 2048) + scolb;

  const int nktA = 4 * pr + 4;
  const int NS = 36;

  auto stage = [&](int sq, int kb) {
    char* kd = (char*)&Klds[0][0] + (sq & 3) * 8192 + wv * 1024;
    char* vd = (char*)&Vlds[0][0] + (sq & 3) * 8192 + wv * 1024;
    __builtin_amdgcn_global_load_lds((const AS1 void*)(ksrc + (size_t)kb * 4096),
                                     (AS3 void*)kd, 16, 0, 0);
    __builtin_amdgcn_global_load_lds((const AS1 void*)(vsrc + kb * 2),
                                     (AS3 void*)vd, 16, 0, 0);
  };

  stage(0, 0);
  stage(1, (1 < nktA ? 1 : 1 - nktA) * 64);

  int seq = 0;
  for (int ph = 0; ph < 2; ++ph) {
    const int qt = ph ? 7 - pr : pr;
    const int nkt = 4 * qt + 4;
    const int qw0 = qt * 256 + wv * 32;
    const int q = qw0 + lq;

    const u16* qp = QK + (size_t)(b * S_ + q) * 2048 + h * E_;
    bf16x8 qf[4];
#pragma unroll
    for (int c = 0; c < 4; ++c)
      qf[c] = *(const bf16x8*)(qp + c * 16 + hi * 8);

    float m_run = -INFINITY, l_part = 0.f;
    f32x16 o0 = {}, o1 = {};

    for (int kt = 0; kt < nkt; ++kt, ++seq) {
      if (seq + 2 < NS) {
        int s2 = seq + 2;
        stage(s2, (s2 < nktA ? s2 : s2 - nktA) * 64);
      }
      if (seq < NS - 2)       asm volatile("s_waitcnt vmcnt(4)" ::: "memory");
      else if (seq == NS - 2) asm volatile("s_waitcnt vmcnt(2)" ::: "memory");
      else                    asm volatile("s_waitcnt vmcnt(0)" ::: "memory");
      __builtin_amdgcn_s_barrier();

      const int kb = kt * 64;
      if (kb > qw0 + 31) continue;         // fully masked for this wave
      const char* kbuf = (const char*)&Klds[0][0] + (seq & 3) * 8192;
      const char* vbuf = (const char*)&Vlds[0][0] + (seq & 3) * 8192;

      auto half = [&](int kb2) __attribute__((always_inline)) {
        f32x16 sc = {};
        __builtin_amdgcn_s_setprio(1);
        const int krow = kb2 * 32 + lq;
#pragma unroll
        for (int c = 0; c < 4; ++c) {
          bf16x8 kf = *(const bf16x8*)(kbuf + krow * 128 +
                                       ((c * 32 + hi * 16) ^ SWZ(krow)));
          sc = __builtin_amdgcn_mfma_f32_32x32x16_bf16(kf, qf[c], sc, 0, 0, 0);
        }
        __builtin_amdgcn_s_setprio(0);

        if (kb + kb2 * 32 + 31 > qw0) {
#pragma unroll
          for (int r = 0; r < 16; ++r) {
            int key = kb + kb2 * 32 + (r & 3) + 8 * (r >> 2) + 4 * hi;
            if (key > q) sc[r] = -1e30f;
          }
        }

        float pm = sc[0];
#pragma unroll
        for (int r = 1; r < 16; ++r) pm = fmaxf(pm, sc[r]);
        if (__any(pm - m_run > 8.0f)) {
          float g = fmaxf(pm, __shfl_xor(pm, 32, 64));
          float mn = fmaxf(m_run, g);
          float corr = exp2f(m_run - mn);
          m_run = mn;
          l_part *= corr;
          o0 *= corr;
          o1 *= corr;
        }

        float p[16];
#pragma unroll
        for (int r = 0; r < 16; ++r) {
          p[r] = exp2f(sc[r] - m_run);
          l_part += p[r];
        }
        __builtin_amdgcn_s_setprio(1);
#pragma unroll
        for (int gg = 0; gg < 2; ++gg) {
          union { unsigned w[4]; bf16x8 v; } pf;
          pf.w[0] = pk2(p[gg * 8 + 0], p[gg * 8 + 1]);
          pf.w[1] = pk2(p[gg * 8 + 2], p[gg * 8 + 3]);
          pf.w[2] = pk2(p[gg * 8 + 4], p[gg * 8 + 5]);
          pf.w[3] = pk2(p[gg * 8 + 6], p[gg * 8 + 7]);
          const int g = kb2 * 2 + gg;
          {
            bf16x8 vf = *(const bf16x8*)(vbuf + lq * 128 +
                                         ((g * 32 + hi * 16) ^ SWZ(lq)));
            o0 = __builtin_amdgcn_mfma_f32_32x32x16_bf16(vf, pf.v, o0, 0, 0, 0);
          }
          {
            const int er = 32 + lq;
            bf16x8 vf = *(const bf16x8*)(vbuf + er * 128 +
                                         ((g * 32 + hi * 16) ^ SWZ(er)));
            o1 = __builtin_amdgcn_mfma_f32_32x32x16_bf16(vf, pf.v, o1, 0, 0, 0);
          }
        }
        __builtin_amdgcn_s_setprio(0);
      };

      half(0);
      if (kb + 32 <= qw0 + 31) half(1);
    }

    float l = l_part + __shfl_xor(l_part, 32, 64);
    float rl = 1.0f / l;

#pragma unroll
    for (int qd = 0; qd < 4; ++qd) {
      u16x4 w0, w1;
#pragma unroll
      for (int j = 0; j < 4; ++j) {
        w0[j] = f2bf(o0[qd * 4 + j] * rl);
        w1[j] = f2bf(o1[qd * 4 + j] * rl);
      }
      const size_t base = (size_t)(b * S_ + q) * D_ + h * E_ + 8 * qd + 4 * hi;
      *(u16x4*)&AO[base] = w0;
      *(u16x4*)&AO[base + 32] = w1;
    }
  }
}

// ---------------- launcher ----------------

extern "C" void kernel_launch(void* const* d_in, const int* in_sizes, int n_in,
                              void* d_out, int out_size, void* d_ws, size_t ws_size,
                              hipStream_t stream) {
  const float* embedded = (const float*)d_in[0];
  const float* Wq = (const float*)d_in[1];
  const float* Wk = (const float*)d_in[2];
  const float* Wv = (const float*)d_in[3];
  const float* Wo = (const float*)d_in[4];
  const float* bo = (const float*)d_in[5];
  float* out = (float*)d_out;

  char* ws = (char*)d_ws;
  u16* X    = (u16*)(ws);                     // [8192][1024]  16 MiB @ 0
  u16* Wqkv = (u16*)(ws + (16u << 20));       // [3072][1024]   6 MiB @ 16M
  u16* WoT  = (u16*)(ws + (22u << 20));       // [1024][1024]   2 MiB @ 22M
  u16* QK   = (u16*)(ws + (24u << 20));       // [8192][2048]  32 MiB @ 24M
  u16* Vt   = (u16*)(ws + (56u << 20));       // [64][64][2048] 16 MiB @ 56M
  u16* AO   = (u16*)(ws + (72u << 20));       // [8192][1024]  16 MiB @ 72M

  // 1) all input conversions, one launch
  cvt_fused<<<9472, 256, 0, stream>>>(embedded, Wo, Wq, Wk, Wv, X, WoT, Wqkv);
  // 2) QKV projection: 256x384 BK=32 ring-3 (Q pre-scaled, V -> sigma Vt)
  gemm_qkv<<<dim3(32, 8), 512, 0, stream>>>(X, Wqkv, QK, Vt);
  // 3) causal flash attention (8-wave, 32x32, counted-vmcnt ring)
  attn<<<256, 512, 0, stream>>>(QK, Vt, AO);
  // 4) output projection + bias -> fp32 d_out (256x128 BK=32 ring-3)
  gemm_out<<<dim3(32, 8), 512, 0, stream>>>(AO, WoT, out, bo);
}

// Round 14
// 175.853 us; speedup vs baseline: 1.3376x; 1.0292x over previous
//
#include <hip/hip_runtime.h>
#include <hip/hip_bf16.h>

// Problem: B=4, S=2048, D=1024, H=16, E=64
#define B_ 4
#define S_ 2048
#define D_ 1024
#define H_ 16
#define E_ 64
#define M_ (B_*S_)      // 8192 rows
#define NQKV_ 3072

typedef __attribute__((ext_vector_type(8))) short bf16x8;
typedef __attribute__((ext_vector_type(4))) float f32x4;
typedef __attribute__((ext_vector_type(16))) float f32x16;
typedef __attribute__((ext_vector_type(4))) unsigned short u16x4;
typedef unsigned short u16;

#define QSCALE 0.18033688011f   // log2(e)/8: folded into Q at GEMM epilogue
#define AS1 __attribute__((address_space(1)))
#define AS3 __attribute__((address_space(3)))

// XOR swizzle on 16B slots within a 128-B row (attn; session-verified)
#define SWZ(r) ((((r) & 7) ^ ((((r) >> 3) & 3) << 1)) << 4)
// XOR swizzle on 16B slots within a 64-B row (BK=32 GEMM tiles): spreads
// same-slot rows across the 4 slot groups; residual ~4-way = geometry floor.
#define SWZ64(r) (((((r) & 3) ^ (((r) >> 2) & 3))) << 4)

static __device__ __forceinline__ u16 f2bf(float f) {
  unsigned u = __builtin_bit_cast(unsigned, f);
  unsigned r = (u + 0x7FFFu + ((u >> 16) & 1u)) >> 16;
  return (u16)r;
}

// packed RNE f32x2 -> bf16x2 (low = a, high = b)
static __device__ __forceinline__ unsigned pk2(float a, float b) {
  unsigned r;
  asm("v_cvt_pk_bf16_f32 %0, %1, %2" : "=v"(r) : "v"(a), "v"(b));
  return r;
}

// ---------------- fused conversion kernel (verified R13) ----------------

__global__ __launch_bounds__(256) void cvt_fused(const float* __restrict__ emb,
                                                 const float* __restrict__ Wo,
                                                 const float* __restrict__ Wq,
                                                 const float* __restrict__ Wk,
                                                 const float* __restrict__ Wv,
                                                 u16* __restrict__ X,
                                                 u16* __restrict__ WoT,
                                                 u16* __restrict__ Wt) {
  __shared__ float t[64][65];
  const int bid = blockIdx.x;
  const int tid = threadIdx.x;
  if (bid < 8192) {
    int i = bid * 256 + tid;
    f32x4 v = ((const f32x4*)emb)[i];
    u16x4 o;
    o.x = f2bf(v.x); o.y = f2bf(v.y); o.z = f2bf(v.z); o.w = f2bf(v.w);
    ((u16x4*)X)[i] = o;
  } else if (bid < 9216) {
    int i = (bid - 8192) * 256 + tid;
    f32x4 v = ((const f32x4*)Wo)[i];
    u16x4 o;
    o.x = f2bf(v.x); o.y = f2bf(v.y); o.z = f2bf(v.z); o.w = f2bf(v.w);
    ((u16x4*)WoT)[i] = o;
  } else {
    const int blk = bid - 9216;
    const int h = blk >> 4;
    const int db = (blk & 15) * 64;
    const float* srcs[3] = {Wq, Wk, Wv};
#pragma unroll
    for (int m = 0; m < 3; ++m) {
      const float* src = srcs[m] + (size_t)h * 65536 + (size_t)db * 64;
      __syncthreads();
#pragma unroll
      for (int i = 0; i < 16; ++i) {
        int idx = i * 256 + tid;
        int d = idx >> 6, e = idx & 63;
        t[e][d] = src[d * 64 + e];
      }
      __syncthreads();
      u16* dst = Wt + (size_t)(m * 1024 + h * 64) * 1024 + db;
#pragma unroll
      for (int i = 0; i < 16; ++i) {
        int idx = i * 256 + tid;
        int e = idx >> 6, d = idx & 63;
        dst[(size_t)e * 1024 + d] = f2bf(t[e][d]);
      }
    }
  }
}

// -------- QKV GEMM in the attn regime: 256x128, 32x32x16 MFMA -------------
// C[8192,3072] = X[8192,1024] * Wqkv[3072,1024]^T.
// 8 waves (4M x 2N), per-wave 64x64 = acc[2][2] f32x16.  BK=32, ring-3 LDS
// (72 KB -> 2 blocks/CU), counted vmcnt(6/3/0), setprio.  This clones the
// execution regime of the attn kernel (the only kernel in this session to
// beat the ~550 TF GEMM plateau per-FLOP): 32x32 MFMA, small LDS, 2 blk/CU.
// Operand map (verified via attn QK^T): A/B row = lane&31, k = (lane>>5)*8+j.
// C map (HW-verified): col = lane&31, row = (r&3)+8*(r>>2)+4*(lane>>5).
// Epilogue regions: c<1024 Q*QSCALE, c<2048 K, c>=2048 V -> sigma-Vt.

__global__ __launch_bounds__(512, 4) void gemm_qkv(const u16* __restrict__ A,
                                                   const u16* __restrict__ Bt,
                                                   u16* __restrict__ QK,
                                                   u16* __restrict__ Vt) {
  __shared__ u16 As[3][256 * 32];    // 16 KB per buffer
  __shared__ u16 Bs[3][128 * 32];    // 8 KB per buffer   (72 KB total)
  const int tid = threadIdx.x;
  const int lane = tid & 63, wv = tid >> 6;
  const int lq = lane & 31, hi = lane >> 5;
  const int wm = wv >> 1, wn = wv & 1;        // 4M x 2N wave grid
  const int bm = blockIdx.x, bn = blockIdx.y;

  // staging sources (K-tile 0); inverse-swizzled col within 64-B row
  const int srow = tid >> 2;                  // 0..127
  const int scb = ((tid & 3) * 16) ^ SWZ64(srow);  // SWZ64(r+128)==SWZ64(r)
  const char* a0 = (const char*)(A + (size_t)(bm * 256 + srow) * 1024) + scb;
  const char* a1 = (const char*)(A + (size_t)(bm * 256 + 128 + srow) * 1024) + scb;
  const char* b0 = (const char*)(Bt + (size_t)(bn * 128 + srow) * 1024) + scb;

  auto stage = [&](int t, int bi) {
    const size_t adv = (size_t)t * 64;        // BK=32 elems * 2 B
    char* ad = (char*)&As[bi][0] + tid * 16;
    char* bd = (char*)&Bs[bi][0] + tid * 16;
    __builtin_amdgcn_global_load_lds((const AS1 void*)(a0 + adv), (AS3 void*)ad, 16, 0, 0);
    __builtin_amdgcn_global_load_lds((const AS1 void*)(a1 + adv), (AS3 void*)(ad + 8192), 16, 0, 0);
    __builtin_amdgcn_global_load_lds((const AS1 void*)(b0 + adv), (AS3 void*)bd, 16, 0, 0);
  };

  f32x16 acc[2][2] = {};

  stage(0, 0);
  stage(1, 1);
  for (int t = 0; t < 32; ++t) {
    const int cur = t % 3;
    if (t + 2 < 32) {
      stage(t + 2, (t + 2) % 3);
      asm volatile("s_waitcnt vmcnt(6)" ::: "memory");
    } else if (t + 1 < 32) {
      asm volatile("s_waitcnt vmcnt(3)" ::: "memory");
    } else {
      asm volatile("s_waitcnt vmcnt(0)" ::: "memory");
    }
    __builtin_amdgcn_s_barrier();

    const char* ab = (const char*)&As[cur][0];
    const char* bb = (const char*)&Bs[cur][0];

    bf16x8 af[2][2], bfr[2][2];
#pragma unroll
    for (int mi = 0; mi < 2; ++mi) {
      int row = wm * 64 + mi * 32 + lq;
#pragma unroll
      for (int ks = 0; ks < 2; ++ks)
        af[mi][ks] = *(const bf16x8*)(ab + row * 64 +
                                      ((ks * 32 + hi * 16) ^ SWZ64(row)));
    }
#pragma unroll
    for (int ni = 0; ni < 2; ++ni) {
      int row = wn * 64 + ni * 32 + lq;
#pragma unroll
      for (int ks = 0; ks < 2; ++ks)
        bfr[ni][ks] = *(const bf16x8*)(bb + row * 64 +
                                       ((ks * 32 + hi * 16) ^ SWZ64(row)));
    }
    __builtin_amdgcn_s_setprio(1);
#pragma unroll
    for (int ks = 0; ks < 2; ++ks)
#pragma unroll
      for (int mi = 0; mi < 2; ++mi)
#pragma unroll
        for (int ni = 0; ni < 2; ++ni)
          acc[mi][ni] = __builtin_amdgcn_mfma_f32_32x32x16_bf16(
              af[mi][ks], bfr[ni][ks], acc[mi][ni], 0, 0, 0);
    __builtin_amdgcn_s_setprio(0);
    __builtin_amdgcn_s_barrier();
  }

  // epilogue: C row = r0 + (r&3) + 8*(r>>2) + 4*hi, col = colg
#pragma unroll
  for (int mi = 0; mi < 2; ++mi) {
#pragma unroll
    for (int ni = 0; ni < 2; ++ni) {
      const int colg = bn * 128 + wn * 64 + ni * 32 + lq;
      const int r0 = bm * 256 + wm * 64 + mi * 32;     // multiple of 32
      if (colg >= 2048) {                              // V -> sigma-perm Vt
        const int e = colg - 2048;
#pragma unroll
        for (int q4 = 0; q4 < 4; ++q4) {
          int tok = r0 + 8 * q4 + 4 * hi;              // j=0 token (mult of 4)
          int bb2 = tok >> 11, s0 = tok & 2047;
          int blk = (s0 >> 2) & 3;
          int s0p = (s0 & ~15) | ((((blk & 1) << 1) | (blk >> 1)) << 2);
          u16x4 pkv;
          pkv.x = f2bf(acc[mi][ni][q4 * 4 + 0]);
          pkv.y = f2bf(acc[mi][ni][q4 * 4 + 1]);
          pkv.z = f2bf(acc[mi][ni][q4 * 4 + 2]);
          pkv.w = f2bf(acc[mi][ni][q4 * 4 + 3]);
          *(u16x4*)&Vt[((size_t)(bb2 * 1024 + e)) * 2048 + s0p] = pkv;
        }
      } else {
        const float qs = (colg < 1024) ? QSCALE : 1.0f;
#pragma unroll
        for (int r = 0; r < 16; ++r) {
          int row = r0 + (r & 3) + 8 * (r >> 2) + 4 * hi;
          QK[(size_t)row * 2048 + colg] = f2bf(acc[mi][ni][r] * qs);
        }
      }
    }
  }
}

// -------- out-proj GEMM in the attn regime: 128x128, 32x32x16, 4 waves ----
// out[8192,1024] = AO[8192,1024] * WoT[1024,1024]^T + bias (fp32 out).
// 4 waves (2M x 2N) of 64x64; BK=32 ring-3 (48 KB -> 3 blocks/CU).

__global__ __launch_bounds__(256, 3) void gemm_out(const u16* __restrict__ A,
                                                   const u16* __restrict__ Bt,
                                                   float* __restrict__ C,
                                                   const float* __restrict__ bias) {
  __shared__ u16 As[3][128 * 32];    // 8 KB per buffer
  __shared__ u16 Bs[3][128 * 32];    // 8 KB per buffer  (48 KB total)
  const int tid = threadIdx.x;
  const int lane = tid & 63, wv = tid >> 6;
  const int lq = lane & 31, hi = lane >> 5;
  const int wm = wv >> 1, wn = wv & 1;        // 2M x 2N wave grid
  const int bm = blockIdx.x, bn = blockIdx.y;

  const int srow = tid >> 2;                  // 0..63
  const int scb0 = ((tid & 3) * 16) ^ SWZ64(srow);
  const char* a0 = (const char*)(A + (size_t)(bm * 128 + srow) * 1024) + scb0;
  const char* a1 = (const char*)(A + (size_t)(bm * 128 + 64 + srow) * 1024) + scb0;
  const char* b0 = (const char*)(Bt + (size_t)(bn * 128 + srow) * 1024) + scb0;
  const char* b1 = (const char*)(Bt + (size_t)(bn * 128 + 64 + srow) * 1024) + scb0;

  auto stage = [&](int t, int bi) {
    const size_t adv = (size_t)t * 64;
    char* ad = (char*)&As[bi][0] + tid * 16;
    char* bd = (char*)&Bs[bi][0] + tid * 16;
    __builtin_amdgcn_global_load_lds((const AS1 void*)(a0 + adv), (AS3 void*)ad, 16, 0, 0);
    __builtin_amdgcn_global_load_lds((const AS1 void*)(a1 + adv), (AS3 void*)(ad + 4096), 16, 0, 0);
    __builtin_amdgcn_global_load_lds((const AS1 void*)(b0 + adv), (AS3 void*)bd, 16, 0, 0);
    __builtin_amdgcn_global_load_lds((const AS1 void*)(b1 + adv), (AS3 void*)(bd + 4096), 16, 0, 0);
  };

  f32x16 acc[2][2] = {};

  stage(0, 0);
  stage(1, 1);
  for (int t = 0; t < 32; ++t) {
    const int cur = t % 3;
    if (t + 2 < 32) {
      stage(t + 2, (t + 2) % 3);
      asm volatile("s_waitcnt vmcnt(8)" ::: "memory");
    } else if (t + 1 < 32) {
      asm volatile("s_waitcnt vmcnt(4)" ::: "memory");
    } else {
      asm volatile("s_waitcnt vmcnt(0)" ::: "memory");
    }
    __builtin_amdgcn_s_barrier();

    const char* ab = (const char*)&As[cur][0];
    const char* bb = (const char*)&Bs[cur][0];

    bf16x8 af[2][2], bfr[2][2];
#pragma unroll
    for (int mi = 0; mi < 2; ++mi) {
      int row = wm * 64 + mi * 32 + lq;
#pragma unroll
      for (int ks = 0; ks < 2; ++ks)
        af[mi][ks] = *(const bf16x8*)(ab + row * 64 +
                                      ((ks * 32 + hi * 16) ^ SWZ64(row)));
    }
#pragma unroll
    for (int ni = 0; ni < 2; ++ni) {
      int row = wn * 64 + ni * 32 + lq;
#pragma unroll
      for (int ks = 0; ks < 2; ++ks)
        bfr[ni][ks] = *(const bf16x8*)(bb + row * 64 +
                                       ((ks * 32 + hi * 16) ^ SWZ64(row)));
    }
    __builtin_amdgcn_s_setprio(1);
#pragma unroll
    for (int ks = 0; ks < 2; ++ks)
#pragma unroll
      for (int mi = 0; mi < 2; ++mi)
#pragma unroll
        for (int ni = 0; ni < 2; ++ni)
          acc[mi][ni] = __builtin_amdgcn_mfma_f32_32x32x16_bf16(
              af[mi][ks], bfr[ni][ks], acc[mi][ni], 0, 0, 0);
    __builtin_amdgcn_s_setprio(0);
    __builtin_amdgcn_s_barrier();
  }

#pragma unroll
  for (int mi = 0; mi < 2; ++mi) {
#pragma unroll
    for (int ni = 0; ni < 2; ++ni) {
      const int colg = bn * 128 + wn * 64 + ni * 32 + lq;
      const int r0 = bm * 128 + wm * 64 + mi * 32;
      const float bv = bias[colg];
#pragma unroll
      for (int r = 0; r < 16; ++r) {
        int row = r0 + (r & 3) + 8 * (r >> 2) + 4 * hi;
        C[(size_t)row * 1024 + colg] = acc[mi][ni][r] + bv;
      }
    }
  }
}

// ------- flash attention (causal): 8-wave, QBLK=256, 32x32 MFMA -----------
// (unchanged from R9 — verified)

__global__ __launch_bounds__(512, 2) void attn(const u16* __restrict__ QK,
                                               const u16* __restrict__ Vt,
                                               u16* __restrict__ AO) {
  __shared__ u16 Klds[4][4096];      // ring of [key 0..63][e 0..63], swizzled
  __shared__ u16 Vlds[4][4096];      // ring of V^T [e][key-slot], swizzled

  const int wg = blockIdx.x;                 // 0..255
  const int lin = (wg & 7) * 32 + (wg >> 3);
  const int bh = lin >> 2, pr = lin & 3;
  const int b = bh >> 4, h = bh & 15;
  const int tid = threadIdx.x;
  const int lane = tid & 63, wv = tid >> 6;  // 8 waves
  const int lq = lane & 31, hi = lane >> 5;

  const int srow = tid >> 3;                 // 0..63
  const int scolb = ((tid & 7) * 16) ^ SWZ(srow);
  const char* ksrc = (const char*)(QK + (size_t)(b * S_ + srow) * 2048 + 1024 + h * E_) + scolb;
  const char* vsrc = (const char*)(Vt + (size_t)(bh * 64 + srow) * 2048) + scolb;

  const int nktA = 4 * pr + 4;
  const int NS = 36;

  auto stage = [&](int sq, int kb) {
    char* kd = (char*)&Klds[0][0] + (sq & 3) * 8192 + wv * 1024;
    char* vd = (char*)&Vlds[0][0] + (sq & 3) * 8192 + wv * 1024;
    __builtin_amdgcn_global_load_lds((const AS1 void*)(ksrc + (size_t)kb * 4096),
                                     (AS3 void*)kd, 16, 0, 0);
    __builtin_amdgcn_global_load_lds((const AS1 void*)(vsrc + kb * 2),
                                     (AS3 void*)vd, 16, 0, 0);
  };

  stage(0, 0);
  stage(1, (1 < nktA ? 1 : 1 - nktA) * 64);

  int seq = 0;
  for (int ph = 0; ph < 2; ++ph) {
    const int qt = ph ? 7 - pr : pr;
    const int nkt = 4 * qt + 4;
    const int qw0 = qt * 256 + wv * 32;
    const int q = qw0 + lq;

    const u16* qp = QK + (size_t)(b * S_ + q) * 2048 + h * E_;
    bf16x8 qf[4];
#pragma unroll
    for (int c = 0; c < 4; ++c)
      qf[c] = *(const bf16x8*)(qp + c * 16 + hi * 8);

    float m_run = -INFINITY, l_part = 0.f;
    f32x16 o0 = {}, o1 = {};

    for (int kt = 0; kt < nkt; ++kt, ++seq) {
      if (seq + 2 < NS) {
        int s2 = seq + 2;
        stage(s2, (s2 < nktA ? s2 : s2 - nktA) * 64);
      }
      if (seq < NS - 2)       asm volatile("s_waitcnt vmcnt(4)" ::: "memory");
      else if (seq == NS - 2) asm volatile("s_waitcnt vmcnt(2)" ::: "memory");
      else                    asm volatile("s_waitcnt vmcnt(0)" ::: "memory");
      __builtin_amdgcn_s_barrier();

      const int kb = kt * 64;
      if (kb > qw0 + 31) continue;         // fully masked for this wave
      const char* kbuf = (const char*)&Klds[0][0] + (seq & 3) * 8192;
      const char* vbuf = (const char*)&Vlds[0][0] + (seq & 3) * 8192;

      auto half = [&](int kb2) __attribute__((always_inline)) {
        f32x16 sc = {};
        __builtin_amdgcn_s_setprio(1);
        const int krow = kb2 * 32 + lq;
#pragma unroll
        for (int c = 0; c < 4; ++c) {
          bf16x8 kf = *(const bf16x8*)(kbuf + krow * 128 +
                                       ((c * 32 + hi * 16) ^ SWZ(krow)));
          sc = __builtin_amdgcn_mfma_f32_32x32x16_bf16(kf, qf[c], sc, 0, 0, 0);
        }
        __builtin_amdgcn_s_setprio(0);

        if (kb + kb2 * 32 + 31 > qw0) {
#pragma unroll
          for (int r = 0; r < 16; ++r) {
            int key = kb + kb2 * 32 + (r & 3) + 8 * (r >> 2) + 4 * hi;
            if (key > q) sc[r] = -1e30f;
          }
        }

        float pm = sc[0];
#pragma unroll
        for (int r = 1; r < 16; ++r) pm = fmaxf(pm, sc[r]);
        if (__any(pm - m_run > 8.0f)) {
          float g = fmaxf(pm, __shfl_xor(pm, 32, 64));
          float mn = fmaxf(m_run, g);
          float corr = exp2f(m_run - mn);
          m_run = mn;
          l_part *= corr;
          o0 *= corr;
          o1 *= corr;
        }

        float p[16];
#pragma unroll
        for (int r = 0; r < 16; ++r) {
          p[r] = exp2f(sc[r] - m_run);
          l_part += p[r];
        }
        __builtin_amdgcn_s_setprio(1);
#pragma unroll
        for (int gg = 0; gg < 2; ++gg) {
          union { unsigned w[4]; bf16x8 v; } pf;
          pf.w[0] = pk2(p[gg * 8 + 0], p[gg * 8 + 1]);
          pf.w[1] = pk2(p[gg * 8 + 2], p[gg * 8 + 3]);
          pf.w[2] = pk2(p[gg * 8 + 4], p[gg * 8 + 5]);
          pf.w[3] = pk2(p[gg * 8 + 6], p[gg * 8 + 7]);
          const int g = kb2 * 2 + gg;
          {
            bf16x8 vf = *(const bf16x8*)(vbuf + lq * 128 +
                                         ((g * 32 + hi * 16) ^ SWZ(lq)));
            o0 = __builtin_amdgcn_mfma_f32_32x32x16_bf16(vf, pf.v, o0, 0, 0, 0);
          }
          {
            const int er = 32 + lq;
            bf16x8 vf = *(const bf16x8*)(vbuf + er * 128 +
                                         ((g * 32 + hi * 16) ^ SWZ(er)));
            o1 = __builtin_amdgcn_mfma_f32_32x32x16_bf16(vf, pf.v, o1, 0, 0, 0);
          }
        }
        __builtin_amdgcn_s_setprio(0);
      };

      half(0);
      if (kb + 32 <= qw0 + 31) half(1);
    }

    float l = l_part + __shfl_xor(l_part, 32, 64);
    float rl = 1.0f / l;

#pragma unroll
    for (int qd = 0; qd < 4; ++qd) {
      u16x4 w0, w1;
#pragma unroll
      for (int j = 0; j < 4; ++j) {
        w0[j] = f2bf(o0[qd * 4 + j] * rl);
        w1[j] = f2bf(o1[qd * 4 + j] * rl);
      }
      const size_t base = (size_t)(b * S_ + q) * D_ + h * E_ + 8 * qd + 4 * hi;
      *(u16x4*)&AO[base] = w0;
      *(u16x4*)&AO[base + 32] = w1;
    }
  }
}

// ---------------- launcher ----------------

extern "C" void kernel_launch(void* const* d_in, const int* in_sizes, int n_in,
                              void* d_out, int out_size, void* d_ws, size_t ws_size,
                              hipStream_t stream) {
  const float* embedded = (const float*)d_in[0];
  const float* Wq = (const float*)d_in[1];
  const float* Wk = (const float*)d_in[2];
  const float* Wv = (const float*)d_in[3];
  const float* Wo = (const float*)d_in[4];
  const float* bo = (const float*)d_in[5];
  float* out = (float*)d_out;

  char* ws = (char*)d_ws;
  u16* X    = (u16*)(ws);                     // [8192][1024]  16 MiB @ 0
  u16* Wqkv = (u16*)(ws + (16u << 20));       // [3072][1024]   6 MiB @ 16M
  u16* WoT  = (u16*)(ws + (22u << 20));       // [1024][1024]   2 MiB @ 22M
  u16* QK   = (u16*)(ws + (24u << 20));       // [8192][2048]  32 MiB @ 24M
  u16* Vt   = (u16*)(ws + (56u << 20));       // [64][64][2048] 16 MiB @ 56M
  u16* AO   = (u16*)(ws + (72u << 20));       // [8192][1024]  16 MiB @ 72M

  // 1) all input conversions, one launch
  cvt_fused<<<9472, 256, 0, stream>>>(embedded, Wo, Wq, Wk, Wv, X, WoT, Wqkv);
  // 2) QKV projection: 256x128, 32x32 MFMA, ring-3, 2 blocks/CU
  gemm_qkv<<<dim3(32, 24), 512, 0, stream>>>(X, Wqkv, QK, Vt);
  // 3) causal flash attention (8-wave, 32x32, counted-vmcnt ring)
  attn<<<256, 512, 0, stream>>>(QK, Vt, AO);
  // 4) output projection + bias -> fp32 d_out (128x128, 32x32, ring-3)
  gemm_out<<<dim3(64, 8), 256, 0, stream>>>(AO, WoT, out, bo);
}